// Round 1
// baseline (1027.911 us; speedup 1.0000x reference)
//
#include <hip/hip_runtime.h>

// Problem constants: B=2, C=256, X=Y=Z=16 -> N=4096, GROUPS=8, HEADS=8, D=32
#define NB 2
#define NC 256
#define NT 4096
#define NG 8
#define NH 8
#define HD 32
#define EPSV 1e-5f
#define QK_SCALE 0.17677669529663687f  // 1/sqrt(32)

// ---------------- GroupNorm statistics (two-stage, deterministic) ------------
// grid = 16 groups * 32 partials = 512 blocks, 256 threads
__global__ __launch_bounds__(256) void k_stats_partial(const float* __restrict__ x,
                                                       float* __restrict__ part) {
    // group (b,g) owns a contiguous 32*4096 = 131072-float slice
    int bg = blockIdx.x >> 5;
    int p  = blockIdx.x & 31;
    const float4* base = (const float4*)(x + (size_t)bg * 131072 + (size_t)p * 4096);
    float s = 0.f, s2 = 0.f;
#pragma unroll
    for (int i = 0; i < 4; ++i) {
        float4 v = base[threadIdx.x + i * 256];
        s  += v.x + v.y + v.z + v.w;
        s2 += v.x * v.x + v.y * v.y + v.z * v.z + v.w * v.w;
    }
    __shared__ float ss[256], sq[256];
    ss[threadIdx.x] = s; sq[threadIdx.x] = s2;
    __syncthreads();
    for (int off = 128; off > 0; off >>= 1) {
        if (threadIdx.x < off) {
            ss[threadIdx.x] += ss[threadIdx.x + off];
            sq[threadIdx.x] += sq[threadIdx.x + off];
        }
        __syncthreads();
    }
    if (threadIdx.x == 0) {
        part[blockIdx.x * 2 + 0] = ss[0];
        part[blockIdx.x * 2 + 1] = sq[0];
    }
}

// grid = 16 blocks (one per (b,g)), 64 threads
__global__ __launch_bounds__(64) void k_stats_final(const float* __restrict__ part,
                                                    float* __restrict__ stats) {
    int bg = blockIdx.x;
    float s = 0.f, s2 = 0.f;
    if (threadIdx.x < 32) {
        s  = part[(bg * 32 + threadIdx.x) * 2 + 0];
        s2 = part[(bg * 32 + threadIdx.x) * 2 + 1];
    }
#pragma unroll
    for (int off = 16; off > 0; off >>= 1) {
        s  += __shfl_down(s, off);
        s2 += __shfl_down(s2, off);
    }
    if (threadIdx.x == 0) {
        const float inv = 1.0f / 131072.0f;
        float mean = s * inv;
        float var  = s2 * inv - mean * mean;
        stats[bg * 2 + 0] = mean;
        stats[bg * 2 + 1] = rsqrtf(var + EPSV);
    }
}

// ---------------- QKV projection GEMM with fused GroupNorm on B --------------
// qkv[b,o,n] = sum_c wqkv[o,c] * normalize(x[b,c,n]) ; o in [0,768)
// grid = (NT/64, 768/64, NB), block 256
__global__ __launch_bounds__(256) void k_qkv(const float* __restrict__ x,
                                             const float* __restrict__ wqkv,
                                             const float* __restrict__ nw,
                                             const float* __restrict__ nb,
                                             const float* __restrict__ stats,
                                             float* __restrict__ qkv) {
    __shared__ float As[32][68];
    __shared__ float Bs[32][68];
    int b = blockIdx.z, o0 = blockIdx.y * 64, n0 = blockIdx.x * 64;
    int tid = threadIdx.x, tx = tid & 15, ty = tid >> 4;
    float acc[4][4] = {};
    for (int c0 = 0; c0 < NC; c0 += 32) {
        int g = c0 >> 5;  // each 32-channel K-tile lies in exactly one group
        float mean = stats[(b * NG + g) * 2 + 0];
        float rstd = stats[(b * NG + g) * 2 + 1];
#pragma unroll
        for (int r = 0; r < 8; ++r) {
            int idx = r * 256 + tid;
            int ol = idx >> 5, cl = idx & 31;
            As[cl][ol] = wqkv[(size_t)(o0 + ol) * NC + c0 + cl];
        }
#pragma unroll
        for (int r = 0; r < 8; ++r) {
            int idx = r * 256 + tid;
            int cl = idx >> 6, nl = idx & 63;
            int c = c0 + cl;
            float v = x[((size_t)(b * NC + c)) * NT + n0 + nl];
            Bs[cl][nl] = (v - mean) * rstd * nw[c] + nb[c];
        }
        __syncthreads();
#pragma unroll
        for (int k = 0; k < 32; ++k) {
            float4 a = *(const float4*)&As[k][ty * 4];
            float4 bv = *(const float4*)&Bs[k][tx * 4];
            float av[4] = {a.x, a.y, a.z, a.w};
            float bw[4] = {bv.x, bv.y, bv.z, bv.w};
#pragma unroll
            for (int i = 0; i < 4; ++i)
#pragma unroll
                for (int j = 0; j < 4; ++j)
                    acc[i][j] += av[i] * bw[j];
        }
        __syncthreads();
    }
#pragma unroll
    for (int i = 0; i < 4; ++i) {
        float4 st = {acc[i][0], acc[i][1], acc[i][2], acc[i][3]};
        *(float4*)&qkv[((size_t)(b * 768 + o0 + ty * 4 + i)) * NT + n0 + tx * 4] = st;
    }
}

// ---------------- Attention: per (b,h), flash-style, fixed-max softmax -------
// grid = NB*NH*(NT/256) = 256 blocks, 256 threads.
// Lane group of 4 cooperates on one query (8 of 32 d's each); 4 queries/thread.
__global__ __launch_bounds__(256) void k_attn(const float* __restrict__ qkv,
                                              float* __restrict__ att) {
    __shared__ float kt[128][36];
    __shared__ float vt[128][36];
    int bid = blockIdx.x;
    int s0 = (bid & 15) << 8;
    int h  = (bid >> 4) & 7;
    int b  = bid >> 7;
    int tid = threadIdx.x;
    int p  = tid & 3;        // d-part: owns d in [p*8, p*8+8)
    int qg = tid >> 2;       // query group 0..63

    size_t qbase = ((size_t)(b * 768 + h * HD)) * NT;
    size_t kbase = ((size_t)(b * 768 + 256 + h * HD)) * NT;
    size_t vbase = ((size_t)(b * 768 + 512 + h * HD)) * NT;

    float qr[4][8];
#pragma unroll
    for (int qq = 0; qq < 4; ++qq) {
        int s = s0 + qg * 4 + qq;
#pragma unroll
        for (int j = 0; j < 8; ++j) {
            int d = p * 8 + j;
            qr[qq][j] = qkv[qbase + (size_t)d * NT + s] * QK_SCALE;
        }
    }
    float acc[4][8] = {};
    float l[4] = {0.f, 0.f, 0.f, 0.f};

    for (int t0 = 0; t0 < NT; t0 += 128) {
        __syncthreads();
#pragma unroll
        for (int r = 0; r < 16; ++r) {
            int idx = r * 256 + tid;
            int d = idx >> 7, tt = idx & 127;
            kt[tt][d] = qkv[kbase + (size_t)d * NT + t0 + tt];
            vt[tt][d] = qkv[vbase + (size_t)d * NT + t0 + tt];
        }
        __syncthreads();
#pragma unroll 2
        for (int t = 0; t < 128; ++t) {
            float4 k0 = *(const float4*)&kt[t][p * 8];
            float4 k1 = *(const float4*)&kt[t][p * 8 + 4];
            float pd[4];
#pragma unroll
            for (int qq = 0; qq < 4; ++qq) {
                pd[qq] = qr[qq][0] * k0.x + qr[qq][1] * k0.y + qr[qq][2] * k0.z +
                         qr[qq][3] * k0.w + qr[qq][4] * k1.x + qr[qq][5] * k1.y +
                         qr[qq][6] * k1.z + qr[qq][7] * k1.w;
            }
#pragma unroll
            for (int qq = 0; qq < 4; ++qq) {
                pd[qq] += __shfl_xor(pd[qq], 1);
                pd[qq] += __shfl_xor(pd[qq], 2);
                // logits are bounded (|logit| << 80): fixed-max softmax, no rescale
                pd[qq] = __expf(pd[qq]);
                l[qq] += pd[qq];
            }
            float4 v0 = *(const float4*)&vt[t][p * 8];
            float4 v1 = *(const float4*)&vt[t][p * 8 + 4];
#pragma unroll
            for (int qq = 0; qq < 4; ++qq) {
                acc[qq][0] += pd[qq] * v0.x;
                acc[qq][1] += pd[qq] * v0.y;
                acc[qq][2] += pd[qq] * v0.z;
                acc[qq][3] += pd[qq] * v0.w;
                acc[qq][4] += pd[qq] * v1.x;
                acc[qq][5] += pd[qq] * v1.y;
                acc[qq][6] += pd[qq] * v1.z;
                acc[qq][7] += pd[qq] * v1.w;
            }
        }
    }
#pragma unroll
    for (int qq = 0; qq < 4; ++qq) {
        float rl = 1.0f / l[qq];
        int s = s0 + qg * 4 + qq;
#pragma unroll
        for (int j = 0; j < 8; ++j) {
            int d = p * 8 + j;
            att[((size_t)(b * NC + h * HD + d)) * NT + s] = acc[qq][j] * rl;
        }
    }
}

// ---------------- Output projection GEMM + bias + residual -------------------
// out[b,o,n] = sum_c wout[o,c]*att[b,c,n] + bout[o] + x[b,o,n]
// grid = (NT/64, NC/64, NB), block 256
__global__ __launch_bounds__(256) void k_out(const float* __restrict__ att,
                                             const float* __restrict__ wout,
                                             const float* __restrict__ bout,
                                             const float* __restrict__ x,
                                             float* __restrict__ out) {
    __shared__ float As[32][68];
    __shared__ float Bs[32][68];
    int b = blockIdx.z, o0 = blockIdx.y * 64, n0 = blockIdx.x * 64;
    int tid = threadIdx.x, tx = tid & 15, ty = tid >> 4;
    float acc[4][4] = {};
    for (int c0 = 0; c0 < NC; c0 += 32) {
#pragma unroll
        for (int r = 0; r < 8; ++r) {
            int idx = r * 256 + tid;
            int ol = idx >> 5, cl = idx & 31;
            As[cl][ol] = wout[(size_t)(o0 + ol) * NC + c0 + cl];
        }
#pragma unroll
        for (int r = 0; r < 8; ++r) {
            int idx = r * 256 + tid;
            int cl = idx >> 6, nl = idx & 63;
            Bs[cl][nl] = att[((size_t)(b * NC + c0 + cl)) * NT + n0 + nl];
        }
        __syncthreads();
#pragma unroll
        for (int k = 0; k < 32; ++k) {
            float4 a = *(const float4*)&As[k][ty * 4];
            float4 bv = *(const float4*)&Bs[k][tx * 4];
            float av[4] = {a.x, a.y, a.z, a.w};
            float bw[4] = {bv.x, bv.y, bv.z, bv.w};
#pragma unroll
            for (int i = 0; i < 4; ++i)
#pragma unroll
                for (int j = 0; j < 4; ++j)
                    acc[i][j] += av[i] * bw[j];
        }
        __syncthreads();
    }
#pragma unroll
    for (int i = 0; i < 4; ++i) {
        int o = o0 + ty * 4 + i;
        float bo = bout[o];
        size_t rowoff = ((size_t)(b * NC + o)) * NT + n0 + tx * 4;
        float4 xr = *(const float4*)&x[rowoff];
        float4 st = {acc[i][0] + bo + xr.x, acc[i][1] + bo + xr.y,
                     acc[i][2] + bo + xr.z, acc[i][3] + bo + xr.w};
        *(float4*)&out[rowoff] = st;
    }
}

extern "C" void kernel_launch(void* const* d_in, const int* in_sizes, int n_in,
                              void* d_out, int out_size, void* d_ws, size_t ws_size,
                              hipStream_t stream) {
    const float* x    = (const float*)d_in[0];
    const float* nw   = (const float*)d_in[1];
    const float* nb   = (const float*)d_in[2];
    const float* wqkv = (const float*)d_in[3];
    const float* wout = (const float*)d_in[4];
    const float* bout = (const float*)d_in[5];
    float* out = (float*)d_out;
    float* ws  = (float*)d_ws;

    float* qkv   = ws;                 // 2*768*4096      = 6291456 floats
    float* att   = ws + 6291456;       // 2*256*4096      = 2097152 floats
    float* part  = ws + 8388608;       // 512*2           = 1024 floats
    float* stats = ws + 8389632;       // 16*2            = 32 floats

    k_stats_partial<<<512, 256, 0, stream>>>(x, part);
    k_stats_final<<<16, 64, 0, stream>>>(part, stats);
    k_qkv<<<dim3(NT / 64, 768 / 64, NB), 256, 0, stream>>>(x, wqkv, nw, nb, stats, qkv);
    k_attn<<<256, 256, 0, stream>>>(qkv, att);
    k_out<<<dim3(NT / 64, NC / 64, NB), 256, 0, stream>>>(att, wout, bout, x, out);
}

// Round 3
// 216.404 us; speedup vs baseline: 4.7500x; 4.7500x over previous
//
#include <hip/hip_runtime.h>

// B=2, C=256, X=Y=Z=16 -> N=4096, GROUPS=8, HEADS=8, D=32
#define NB 2
#define NC 256
#define NT 4096
#define NG 8
#define NH 8
#define EPSV 1e-5f
// (1/sqrt(32)) * log2(e): folded into Q at projection time -> softmax is exp2()
#define SCALE_L2E 0.25503164427f

typedef __attribute__((ext_vector_type(8))) __bf16 bf16x8;
typedef __attribute__((ext_vector_type(8))) unsigned short u16x8;
typedef __attribute__((ext_vector_type(4))) unsigned short u16x4;
typedef __attribute__((ext_vector_type(4))) float f32x4;

static __device__ __forceinline__ unsigned short f2bf(float f) {
    union { float f; unsigned int u; } v; v.f = f;
    unsigned int r = v.u + 0x7fffu + ((v.u >> 16) & 1u);  // RNE
    return (unsigned short)(r >> 16);
}
static __device__ __forceinline__ bf16x8 ldbf8(const unsigned short* p) {
    u16x8 u = *(const u16x8*)p;
    return __builtin_bit_cast(bf16x8, u);
}

// ---------------- GroupNorm statistics (two-stage, deterministic) ------------
__global__ __launch_bounds__(256) void k_stats_partial(const float* __restrict__ x,
                                                       float* __restrict__ part) {
    int bg = blockIdx.x >> 5;
    int p  = blockIdx.x & 31;
    const float4* base = (const float4*)(x + (size_t)bg * 131072 + (size_t)p * 4096);
    float s = 0.f, s2 = 0.f;
#pragma unroll
    for (int i = 0; i < 4; ++i) {
        float4 v = base[threadIdx.x + i * 256];
        s  += v.x + v.y + v.z + v.w;
        s2 += v.x * v.x + v.y * v.y + v.z * v.z + v.w * v.w;
    }
    __shared__ float ss[256], sq[256];
    ss[threadIdx.x] = s; sq[threadIdx.x] = s2;
    __syncthreads();
    for (int off = 128; off > 0; off >>= 1) {
        if (threadIdx.x < off) {
            ss[threadIdx.x] += ss[threadIdx.x + off];
            sq[threadIdx.x] += sq[threadIdx.x + off];
        }
        __syncthreads();
    }
    if (threadIdx.x == 0) {
        part[blockIdx.x * 2 + 0] = ss[0];
        part[blockIdx.x * 2 + 1] = sq[0];
    }
}

__global__ __launch_bounds__(64) void k_stats_final(const float* __restrict__ part,
                                                    float* __restrict__ stats) {
    int bg = blockIdx.x;
    float s = 0.f, s2 = 0.f;
    if (threadIdx.x < 32) {
        s  = part[(bg * 32 + threadIdx.x) * 2 + 0];
        s2 = part[(bg * 32 + threadIdx.x) * 2 + 1];
    }
#pragma unroll
    for (int off = 16; off > 0; off >>= 1) {
        s  += __shfl_down(s, off);
        s2 += __shfl_down(s2, off);
    }
    if (threadIdx.x == 0) {
        const float inv = 1.0f / 131072.0f;
        float mean = s * inv;
        float var  = s2 * inv - mean * mean;
        stats[bg * 2 + 0] = mean;
        stats[bg * 2 + 1] = rsqrtf(var + EPSV);
    }
}

// ---------------- QKV projection GEMM (fp32 core, bf16 transposed epilogue) --
// o in [0,256): Q -> qkT[0][b][h][tok][d] scaled by SCALE_L2E
// o in [256,512): K -> qkT[1][b][h][tok][d]
// o in [512,768): V -> vbf[b][h][d][tok]
__global__ __launch_bounds__(256) void k_qkv(const float* __restrict__ x,
                                             const float* __restrict__ wqkv,
                                             const float* __restrict__ nw,
                                             const float* __restrict__ nbias,
                                             const float* __restrict__ stats,
                                             unsigned short* __restrict__ qkT,
                                             unsigned short* __restrict__ vbf) {
    __shared__ float As[32][68];
    __shared__ float Bs[32][68];
    int b = blockIdx.z, o0 = blockIdx.y * 64, n0 = blockIdx.x * 64;
    int tid = threadIdx.x, tx = tid & 15, ty = tid >> 4;
    float acc[4][4] = {};
    for (int c0 = 0; c0 < NC; c0 += 32) {
        int g = c0 >> 5;
        float mean = stats[(b * NG + g) * 2 + 0];
        float rstd = stats[(b * NG + g) * 2 + 1];
#pragma unroll
        for (int r = 0; r < 8; ++r) {
            int idx = r * 256 + tid;
            int ol = idx >> 5, cl = idx & 31;
            As[cl][ol] = wqkv[(size_t)(o0 + ol) * NC + c0 + cl];
        }
#pragma unroll
        for (int r = 0; r < 8; ++r) {
            int idx = r * 256 + tid;
            int cl = idx >> 6, nl = idx & 63;
            int c = c0 + cl;
            float v = x[((size_t)(b * NC + c)) * NT + n0 + nl];
            Bs[cl][nl] = (v - mean) * rstd * nw[c] + nbias[c];
        }
        __syncthreads();
#pragma unroll
        for (int k = 0; k < 32; ++k) {
            float4 a = *(const float4*)&As[k][ty * 4];
            float4 bv = *(const float4*)&Bs[k][tx * 4];
            float av[4] = {a.x, a.y, a.z, a.w};
            float bw[4] = {bv.x, bv.y, bv.z, bv.w};
#pragma unroll
            for (int i = 0; i < 4; ++i)
#pragma unroll
                for (int j = 0; j < 4; ++j)
                    acc[i][j] += av[i] * bw[j];
        }
        __syncthreads();
    }
    if (blockIdx.y < 8) {
        // Q or K: transposed bf16 store [tok][d] (4 consecutive d = i index)
        int o = o0 + ty * 4;
        int qk = o >> 8;
        int hh = (o >> 5) & 7;
        int d4 = o & 31;
        float sc = (qk == 0) ? SCALE_L2E : 1.0f;
        unsigned short* dst = qkT + ((((size_t)qk * NB + b) * NH + hh) * NT) * 32;
#pragma unroll
        for (int j = 0; j < 4; ++j) {
            int tok = n0 + tx * 4 + j;
            u16x4 pk = { f2bf(acc[0][j] * sc), f2bf(acc[1][j] * sc),
                         f2bf(acc[2][j] * sc), f2bf(acc[3][j] * sc) };
            *(u16x4*)&dst[(size_t)tok * 32 + d4] = pk;
        }
    } else {
        // V: natural [d][tok] bf16 store (4 consecutive tok = j index)
        int o = o0 + ty * 4;
        int hh = (o >> 5) & 7;
        int d = o & 31;
        unsigned short* dst = vbf + (((size_t)b * NH + hh) * 32) * NT;
#pragma unroll
        for (int i = 0; i < 4; ++i) {
            u16x4 pk = { f2bf(acc[i][0]), f2bf(acc[i][1]),
                         f2bf(acc[i][2]), f2bf(acc[i][3]) };
            *(u16x4*)&dst[(size_t)(d + i) * NT + n0 + tx * 4] = pk;
        }
    }
}

// ---------------- Attention: swapped-QK^T bf16 MFMA, no-max softmax ----------
// grid (32, NH, NB), 256 threads = 4 waves; each wave owns 32 queries.
// S^T = mfma(K^T, Q): lane holds col s (one query), rows t -> lane-local denom.
// P staged per-wave in LDS [32s][32t] (XOR-swizzled), no __syncthreads in loop.
__global__ __launch_bounds__(256) void k_attn(const unsigned short* __restrict__ qkT,
                                              const unsigned short* __restrict__ vbf,
                                              float* __restrict__ att) {
    __shared__ unsigned short P[4][1024];
    int sb = blockIdx.x, h = blockIdx.y, b = blockIdx.z;
    int tid = threadIdx.x;
    int w = tid >> 6, lane = tid & 63, col = lane & 15, g = lane >> 4;
    int s0 = sb * 128 + w * 32;

    const unsigned short* qB = qkT + ((((size_t)0 * NB + b) * NH + h) * NT) * 32;
    const unsigned short* kB = qkT + ((((size_t)1 * NB + b) * NH + h) * NT) * 32;
    const unsigned short* vB = vbf + (((size_t)b * NH + h) * 32) * NT;

    // Q fragments (B-operand): col = s, k = d = g*8+j. Scale pre-folded.
    bf16x8 qf[2];
    qf[0] = ldbf8(qB + (size_t)(s0 + col) * 32 + g * 8);
    qf[1] = ldbf8(qB + (size_t)(s0 + 16 + col) * 32 + g * 8);

    f32x4 oacc[2][2] = {};     // [d-tile][s-tile]
    float lsum[2] = {0.f, 0.f};

    unsigned short* Pw = P[w];
    const unsigned short* kA  = kB + (size_t)col * 32 + g * 8;       // + t*32
    const unsigned short* vA0 = vB + (size_t)col * NT + g * 8;       // d-tile 0
    const unsigned short* vA1 = vB + (size_t)(16 + col) * NT + g * 8;

    bf16x8 kf0 = ldbf8(kA);
    bf16x8 kf1 = ldbf8(kA + 16 * 32);
    bf16x8 vf0 = ldbf8(vA0);
    bf16x8 vf1 = ldbf8(vA1);

    for (int t0 = 0; t0 < NT; t0 += 32) {
        bf16x8 ck0 = kf0, ck1 = kf1, cv0 = vf0, cv1 = vf1;
        if (t0 + 32 < NT) {  // one-tile register prefetch
            kf0 = ldbf8(kA + (size_t)(t0 + 32) * 32);
            kf1 = ldbf8(kA + (size_t)(t0 + 48) * 32);
            vf0 = ldbf8(vA0 + t0 + 32);
            vf1 = ldbf8(vA1 + t0 + 32);
        }
        const f32x4 z = {0.f, 0.f, 0.f, 0.f};
#pragma unroll
        for (int st = 0; st < 2; ++st) {
            int s_l = st * 16 + col;
            int swz = (s_l & 3) << 3;
#pragma unroll
            for (int tt = 0; tt < 2; ++tt) {
                f32x4 sa = __builtin_amdgcn_mfma_f32_16x16x32_bf16(
                    tt ? ck1 : ck0, qf[st], z, 0, 0, 0);
                float p0 = exp2f(sa[0]);
                float p1 = exp2f(sa[1]);
                float p2 = exp2f(sa[2]);
                float p3 = exp2f(sa[3]);
                lsum[st] += (p0 + p1) + (p2 + p3);
                u16x4 pk = { f2bf(p0), f2bf(p1), f2bf(p2), f2bf(p3) };
                *(u16x4*)&Pw[(s_l * 32 + tt * 16 + g * 4) ^ swz] = pk;
            }
        }
#pragma unroll
        for (int st = 0; st < 2; ++st) {
            int s_l = st * 16 + col;
            bf16x8 pf = ldbf8(&Pw[(s_l * 32 + g * 8) ^ ((s_l & 3) << 3)]);
            oacc[0][st] = __builtin_amdgcn_mfma_f32_16x16x32_bf16(cv0, pf, oacc[0][st], 0, 0, 0);
            oacc[1][st] = __builtin_amdgcn_mfma_f32_16x16x32_bf16(cv1, pf, oacc[1][st], 0, 0, 0);
        }
    }
#pragma unroll
    for (int st = 0; st < 2; ++st) {
        lsum[st] += __shfl_xor(lsum[st], 16);
        lsum[st] += __shfl_xor(lsum[st], 32);
        lsum[st] = 1.0f / lsum[st];
    }
#pragma unroll
    for (int dt = 0; dt < 2; ++dt)
#pragma unroll
        for (int st = 0; st < 2; ++st)
#pragma unroll
            for (int r = 0; r < 4; ++r) {
                int d = dt * 16 + g * 4 + r;
                int s = s0 + st * 16 + col;
                att[((size_t)(b * NC + h * 32 + d)) * NT + s] = oacc[dt][st][r] * lsum[st];
            }
}

// ---------------- Output projection GEMM + bias + residual -------------------
__global__ __launch_bounds__(256) void k_out(const float* __restrict__ att,
                                             const float* __restrict__ wout,
                                             const float* __restrict__ bout,
                                             const float* __restrict__ x,
                                             float* __restrict__ out) {
    __shared__ float As[32][68];
    __shared__ float Bs[32][68];
    int b = blockIdx.z, o0 = blockIdx.y * 64, n0 = blockIdx.x * 64;
    int tid = threadIdx.x, tx = tid & 15, ty = tid >> 4;
    float acc[4][4] = {};
    for (int c0 = 0; c0 < NC; c0 += 32) {
#pragma unroll
        for (int r = 0; r < 8; ++r) {
            int idx = r * 256 + tid;
            int ol = idx >> 5, cl = idx & 31;
            As[cl][ol] = wout[(size_t)(o0 + ol) * NC + c0 + cl];
        }
#pragma unroll
        for (int r = 0; r < 8; ++r) {
            int idx = r * 256 + tid;
            int cl = idx >> 6, nl = idx & 63;
            Bs[cl][nl] = att[((size_t)(b * NC + c0 + cl)) * NT + n0 + nl];
        }
        __syncthreads();
#pragma unroll
        for (int k = 0; k < 32; ++k) {
            float4 a = *(const float4*)&As[k][ty * 4];
            float4 bv = *(const float4*)&Bs[k][tx * 4];
            float av[4] = {a.x, a.y, a.z, a.w};
            float bw[4] = {bv.x, bv.y, bv.z, bv.w};
#pragma unroll
            for (int i = 0; i < 4; ++i)
#pragma unroll
                for (int j = 0; j < 4; ++j)
                    acc[i][j] += av[i] * bw[j];
        }
        __syncthreads();
    }
#pragma unroll
    for (int i = 0; i < 4; ++i) {
        int o = o0 + ty * 4 + i;
        float bo = bout[o];
        size_t rowoff = ((size_t)(b * NC + o)) * NT + n0 + tx * 4;
        float4 xr = *(const float4*)&x[rowoff];
        float4 st = {acc[i][0] + bo + xr.x, acc[i][1] + bo + xr.y,
                     acc[i][2] + bo + xr.z, acc[i][3] + bo + xr.w};
        *(float4*)&out[rowoff] = st;
    }
}

extern "C" void kernel_launch(void* const* d_in, const int* in_sizes, int n_in,
                              void* d_out, int out_size, void* d_ws, size_t ws_size,
                              hipStream_t stream) {
    const float* x    = (const float*)d_in[0];
    const float* nw   = (const float*)d_in[1];
    const float* nb   = (const float*)d_in[2];
    const float* wqkv = (const float*)d_in[3];
    const float* wout = (const float*)d_in[4];
    const float* bout = (const float*)d_in[5];
    float* out = (float*)d_out;
    char* wsb = (char*)d_ws;

    unsigned short* qkT = (unsigned short*)wsb;                        // 8 MB: [2][B][H][4096][32]
    unsigned short* vbf = (unsigned short*)(wsb + 8u * 1024 * 1024);   // 4 MB: [B][H][32][4096]
    float* att   = (float*)(wsb + 12u * 1024 * 1024);                  // 8 MB: [B][C][N]
    float* part  = (float*)(wsb + 20u * 1024 * 1024);
    float* stats = part + 1024;

    k_stats_partial<<<512, 256, 0, stream>>>(x, part);
    k_stats_final<<<16, 64, 0, stream>>>(part, stats);
    k_qkv<<<dim3(NT / 64, 768 / 64, NB), 256, 0, stream>>>(x, wqkv, nw, nb, stats, qkT, vbf);
    k_attn<<<dim3(32, NH, NB), 256, 0, stream>>>(qkT, vbf, att);
    k_out<<<dim3(NT / 64, NC / 64, NB), 256, 0, stream>>>(att, wout, bout, x, out);
}

// Round 5
// 183.548 us; speedup vs baseline: 5.6002x; 1.1790x over previous
//
#include <hip/hip_runtime.h>

// B=2, C=256, X=Y=Z=16 -> N=4096, GROUPS=8, HEADS=8, D=32
#define NB 2
#define NC 256
#define NT 4096
#define NG 8
#define NH 8
#define EPSV 1e-5f
// (1/sqrt(32)) * log2(e): folded into Q at projection time -> softmax is exp2()
#define SCALE_L2E 0.25503164427f
#define NCHUNK 2
#define CHTOK (NT / NCHUNK)          // 2048 tokens per chunk
#define PO_STRIDE ((size_t)NB * NC * NT)   // floats per chunk of partial O

typedef __attribute__((ext_vector_type(8))) __bf16 bf16x8;
typedef __attribute__((ext_vector_type(8))) unsigned short u16x8;
typedef __attribute__((ext_vector_type(4))) unsigned short u16x4;
typedef __attribute__((ext_vector_type(4))) unsigned int u32x4;
typedef __attribute__((ext_vector_type(2))) unsigned int u32x2;
typedef __attribute__((ext_vector_type(4))) float f32x4;

static __device__ __forceinline__ unsigned short f2bf(float f) {
    union { float f; unsigned int u; } v; v.f = f;
    unsigned int r = v.u + 0x7fffu + ((v.u >> 16) & 1u);  // RNE
    return (unsigned short)(r >> 16);
}
static __device__ __forceinline__ bf16x8 ldbf8(const unsigned short* p) {
    u16x8 u = *(const u16x8*)p;
    return __builtin_bit_cast(bf16x8, u);
}
static __device__ __forceinline__ unsigned int cvtpk(float lo, float hi) {
    unsigned int d;
    asm("v_cvt_pk_bf16_f32 %0, %1, %2" : "=v"(d) : "v"(lo), "v"(hi));
    return d;
}

// ---------------- GroupNorm statistics (two-stage, deterministic) ------------
__global__ __launch_bounds__(256) void k_stats_partial(const float* __restrict__ x,
                                                       float* __restrict__ part) {
    int bg = blockIdx.x >> 5;
    int p  = blockIdx.x & 31;
    const float4* base = (const float4*)(x + (size_t)bg * 131072 + (size_t)p * 4096);
    float s = 0.f, s2 = 0.f;
#pragma unroll
    for (int i = 0; i < 4; ++i) {
        float4 v = base[threadIdx.x + i * 256];
        s  += v.x + v.y + v.z + v.w;
        s2 += v.x * v.x + v.y * v.y + v.z * v.z + v.w * v.w;
    }
    __shared__ float ss[256], sq[256];
    ss[threadIdx.x] = s; sq[threadIdx.x] = s2;
    __syncthreads();
    for (int off = 128; off > 0; off >>= 1) {
        if (threadIdx.x < off) {
            ss[threadIdx.x] += ss[threadIdx.x + off];
            sq[threadIdx.x] += sq[threadIdx.x + off];
        }
        __syncthreads();
    }
    if (threadIdx.x == 0) {
        part[blockIdx.x * 2 + 0] = ss[0];
        part[blockIdx.x * 2 + 1] = sq[0];
    }
}

__global__ __launch_bounds__(64) void k_stats_final(const float* __restrict__ part,
                                                    float* __restrict__ stats) {
    int bg = blockIdx.x;
    float s = 0.f, s2 = 0.f;
    if (threadIdx.x < 32) {
        s  = part[(bg * 32 + threadIdx.x) * 2 + 0];
        s2 = part[(bg * 32 + threadIdx.x) * 2 + 1];
    }
#pragma unroll
    for (int off = 16; off > 0; off >>= 1) {
        s  += __shfl_down(s, off);
        s2 += __shfl_down(s2, off);
    }
    if (threadIdx.x == 0) {
        const float inv = 1.0f / 131072.0f;
        float mean = s * inv;
        float var  = s2 * inv - mean * mean;
        stats[bg * 2 + 0] = mean;
        stats[bg * 2 + 1] = rsqrtf(var + EPSV);
    }
}

// ---------------- QKV projection GEMM (fp32 core, bf16 transposed epilogue) --
__global__ __launch_bounds__(256) void k_qkv(const float* __restrict__ x,
                                             const float* __restrict__ wqkv,
                                             const float* __restrict__ nw,
                                             const float* __restrict__ nbias,
                                             const float* __restrict__ stats,
                                             unsigned short* __restrict__ qkT,
                                             unsigned short* __restrict__ vbf) {
    __shared__ float As[32][68];
    __shared__ float Bs[32][68];
    int b = blockIdx.z, o0 = blockIdx.y * 64, n0 = blockIdx.x * 64;
    int tid = threadIdx.x, tx = tid & 15, ty = tid >> 4;
    float acc[4][4] = {};
    for (int c0 = 0; c0 < NC; c0 += 32) {
        int g = c0 >> 5;
        float mean = stats[(b * NG + g) * 2 + 0];
        float rstd = stats[(b * NG + g) * 2 + 1];
#pragma unroll
        for (int r = 0; r < 8; ++r) {
            int idx = r * 256 + tid;
            int ol = idx >> 5, cl = idx & 31;
            As[cl][ol] = wqkv[(size_t)(o0 + ol) * NC + c0 + cl];
        }
#pragma unroll
        for (int r = 0; r < 8; ++r) {
            int idx = r * 256 + tid;
            int cl = idx >> 6, nl = idx & 63;
            int c = c0 + cl;
            float v = x[((size_t)(b * NC + c)) * NT + n0 + nl];
            Bs[cl][nl] = (v - mean) * rstd * nw[c] + nbias[c];
        }
        __syncthreads();
#pragma unroll
        for (int k = 0; k < 32; ++k) {
            float4 a = *(const float4*)&As[k][ty * 4];
            float4 bv = *(const float4*)&Bs[k][tx * 4];
            float av[4] = {a.x, a.y, a.z, a.w};
            float bw[4] = {bv.x, bv.y, bv.z, bv.w};
#pragma unroll
            for (int i = 0; i < 4; ++i)
#pragma unroll
                for (int j = 0; j < 4; ++j)
                    acc[i][j] += av[i] * bw[j];
        }
        __syncthreads();
    }
    if (blockIdx.y < 8) {
        int o = o0 + ty * 4;
        int qk = o >> 8;
        int hh = (o >> 5) & 7;
        int d4 = o & 31;
        float sc = (qk == 0) ? SCALE_L2E : 1.0f;
        unsigned short* dst = qkT + ((((size_t)qk * NB + b) * NH + hh) * NT) * 32;
#pragma unroll
        for (int j = 0; j < 4; ++j) {
            int tok = n0 + tx * 4 + j;
            u16x4 pk = { f2bf(acc[0][j] * sc), f2bf(acc[1][j] * sc),
                         f2bf(acc[2][j] * sc), f2bf(acc[3][j] * sc) };
            *(u16x4*)&dst[(size_t)tok * 32 + d4] = pk;
        }
    } else {
        int o = o0 + ty * 4;
        int hh = (o >> 5) & 7;
        int d = o & 31;
        unsigned short* dst = vbf + (((size_t)b * NH + hh) * 32) * NT;
#pragma unroll
        for (int i = 0; i < 4; ++i) {
            u16x4 pk = { f2bf(acc[i][0]), f2bf(acc[i][1]),
                         f2bf(acc[i][2]), f2bf(acc[i][3]) };
            *(u16x4*)&dst[(size_t)(d + i) * NT + n0 + tx * 4] = pk;
        }
    }
}

// ---------------- Attention: swapped-QK^T bf16 MFMA, split-token -------------
// grid (32, NH, NB*NCHUNK), 256 threads = 4 waves; wave owns 32 queries,
// sweeps its token chunk. Partial (unnormalized O, l) out; no-max softmax.
// l computed via all-ones MFMA (matrix pipe), P staged in padded LDS rows.
__global__ __launch_bounds__(256) void k_attn(const unsigned short* __restrict__ qkT,
                                              const unsigned short* __restrict__ vbf,
                                              float* __restrict__ pO,
                                              float* __restrict__ pl) {
    __shared__ unsigned int Pd[4][32 * 36];   // per-wave: 32 rows x 36 dwords (padded)
    int sb = blockIdx.x, h = blockIdx.y;
    int b  = blockIdx.z >> 1, ch = blockIdx.z & 1;
    int tid = threadIdx.x;
    int w = tid >> 6, lane = tid & 63, col = lane & 15, g = lane >> 4;
    int s0 = sb * 128 + w * 32;

    const unsigned short* qB = qkT + ((((size_t)0 * NB + b) * NH + h) * NT) * 32;
    const unsigned short* kB = qkT + ((((size_t)1 * NB + b) * NH + h) * NT) * 32;
    const unsigned short* vB = vbf + (((size_t)b * NH + h) * 32) * NT;

    // Q fragments (B-operand): col = s, k = d = g*8+j. Scale pre-folded.
    bf16x8 qf[2];
    qf[0] = ldbf8(qB + (size_t)(s0 + col) * 32 + g * 8);
    qf[1] = ldbf8(qB + (size_t)(s0 + 16 + col) * 32 + g * 8);

    u16x8 ou;
#pragma unroll
    for (int j = 0; j < 8; ++j) ou[j] = 0x3F80;  // bf16 1.0
    const bf16x8 ones = __builtin_bit_cast(bf16x8, ou);

    f32x4 oacc[2][2] = {};     // [d-tile][s-tile]
    f32x4 lacc[2] = {};        // [s-tile] partial softmax denominator

    unsigned int* Pw = Pd[w];
    const unsigned short* kA0 = kB + ((size_t)(ch * CHTOK) + col) * 32 + g * 8;
    const unsigned short* vA0 = vB + (size_t)col * NT + ch * CHTOK + g * 8;
    const unsigned short* vA1 = vB + (size_t)(16 + col) * NT + ch * CHTOK + g * 8;

    bf16x8 kf0 = ldbf8(kA0);
    bf16x8 kf1 = ldbf8(kA0 + 512);
    bf16x8 vf0 = ldbf8(vA0);
    bf16x8 vf1 = ldbf8(vA1);

    for (int it = 0; it < CHTOK / 32; ++it) {
        bf16x8 ck0 = kf0, ck1 = kf1, cv0 = vf0, cv1 = vf1;
        if (it + 1 < CHTOK / 32) {  // one-tile register prefetch
            const unsigned short* kn = kA0 + (size_t)(it + 1) * 1024;
            kf0 = ldbf8(kn);
            kf1 = ldbf8(kn + 512);
            vf0 = ldbf8(vA0 + (it + 1) * 32);
            vf1 = ldbf8(vA1 + (it + 1) * 32);
        }
        const f32x4 z = {0.f, 0.f, 0.f, 0.f};
#pragma unroll
        for (int st = 0; st < 2; ++st) {
            int s_l = st * 16 + col;
#pragma unroll
            for (int tt = 0; tt < 2; ++tt) {
                f32x4 sa = __builtin_amdgcn_mfma_f32_16x16x32_bf16(
                    tt ? ck1 : ck0, qf[st], z, 0, 0, 0);
                // no-max softmax: logits bounded, exp2 directly
                unsigned int d0 = cvtpk(__builtin_amdgcn_exp2f(sa[0]),
                                        __builtin_amdgcn_exp2f(sa[1]));
                unsigned int d1 = cvtpk(__builtin_amdgcn_exp2f(sa[2]),
                                        __builtin_amdgcn_exp2f(sa[3]));
                u32x2 wv = {d0, d1};
                *(u32x2*)&Pw[s_l * 36 + tt * 8 + g * 2] = wv;
            }
        }
#pragma unroll
        for (int st = 0; st < 2; ++st) {
            int s_l = st * 16 + col;
            u32x4 rv = *(const u32x4*)&Pw[s_l * 36 + g * 4];
            bf16x8 pf = __builtin_bit_cast(bf16x8, rv);
            lacc[st]     = __builtin_amdgcn_mfma_f32_16x16x32_bf16(ones, pf, lacc[st], 0, 0, 0);
            oacc[0][st]  = __builtin_amdgcn_mfma_f32_16x16x32_bf16(cv0, pf, oacc[0][st], 0, 0, 0);
            oacc[1][st]  = __builtin_amdgcn_mfma_f32_16x16x32_bf16(cv1, pf, oacc[1][st], 0, 0, 0);
        }
    }

    float* pOc = pO + (size_t)ch * PO_STRIDE;
#pragma unroll
    for (int dt = 0; dt < 2; ++dt)
#pragma unroll
        for (int st = 0; st < 2; ++st)
#pragma unroll
            for (int r = 0; r < 4; ++r) {
                int d = dt * 16 + g * 4 + r;
                int s = s0 + st * 16 + col;
                pOc[((size_t)(b * NC + h * 32 + d)) * NT + s] = oacc[dt][st][r];
            }
    if (g == 0) {
#pragma unroll
        for (int st = 0; st < 2; ++st) {
            int s = s0 + st * 16 + col;
            pl[((size_t)(ch * NB + b) * NH + h) * NT + s] = lacc[st][0];
        }
    }
}

// ---------------- Combine partial chunks: att = sum(O) / sum(l) --------------
// att aliases pO chunk 0 (read-then-write per thread, no cross-thread overlap)
__global__ __launch_bounds__(256) void k_combine(const float* __restrict__ pO,
                                                 const float* __restrict__ pl,
                                                 float* __restrict__ att) {
    int f = blockIdx.x * 256 + threadIdx.x;   // float4 index, 524288 total
    int b  = f >> 18;
    int r  = f & 262143;
    int c  = r >> 10;
    int sf = r & 1023;
    int h  = c >> 5;
    float4 o0 = ((const float4*)pO)[f];
    float4 o1 = ((const float4*)pO)[(PO_STRIDE >> 2) + f];
    float4 l0 = ((const float4*)pl)[(size_t)(b * NH + h) * 1024 + sf];
    float4 l1 = ((const float4*)pl)[(size_t)((NB + b) * NH + h) * 1024 + sf];
    float4 res = { (o0.x + o1.x) / (l0.x + l1.x),
                   (o0.y + o1.y) / (l0.y + l1.y),
                   (o0.z + o1.z) / (l0.z + l1.z),
                   (o0.w + o1.w) / (l0.w + l1.w) };
    ((float4*)att)[f] = res;
}

// ---------------- Output projection GEMM + bias + residual -------------------
__global__ __launch_bounds__(256) void k_out(const float* __restrict__ att,
                                             const float* __restrict__ wout,
                                             const float* __restrict__ bout,
                                             const float* __restrict__ x,
                                             float* __restrict__ out) {
    __shared__ float As[32][68];
    __shared__ float Bs[32][68];
    int b = blockIdx.z, o0 = blockIdx.y * 64, n0 = blockIdx.x * 64;
    int tid = threadIdx.x, tx = tid & 15, ty = tid >> 4;
    float acc[4][4] = {};
    for (int c0 = 0; c0 < NC; c0 += 32) {
#pragma unroll
        for (int r = 0; r < 8; ++r) {
            int idx = r * 256 + tid;
            int ol = idx >> 5, cl = idx & 31;
            As[cl][ol] = wout[(size_t)(o0 + ol) * NC + c0 + cl];
        }
#pragma unroll
        for (int r = 0; r < 8; ++r) {
            int idx = r * 256 + tid;
            int cl = idx >> 6, nl = idx & 63;
            Bs[cl][nl] = att[((size_t)(b * NC + c0 + cl)) * NT + n0 + nl];
        }
        __syncthreads();
#pragma unroll
        for (int k = 0; k < 32; ++k) {
            float4 a = *(const float4*)&As[k][ty * 4];
            float4 bv = *(const float4*)&Bs[k][tx * 4];
            float av[4] = {a.x, a.y, a.z, a.w};
            float bw[4] = {bv.x, bv.y, bv.z, bv.w};
#pragma unroll
            for (int i = 0; i < 4; ++i)
#pragma unroll
                for (int j = 0; j < 4; ++j)
                    acc[i][j] += av[i] * bw[j];
        }
        __syncthreads();
    }
#pragma unroll
    for (int i = 0; i < 4; ++i) {
        int o = o0 + ty * 4 + i;
        float bo = bout[o];
        size_t rowoff = ((size_t)(b * NC + o)) * NT + n0 + tx * 4;
        float4 xr = *(const float4*)&x[rowoff];
        float4 st = {acc[i][0] + bo + xr.x, acc[i][1] + bo + xr.y,
                     acc[i][2] + bo + xr.z, acc[i][3] + bo + xr.w};
        *(float4*)&out[rowoff] = st;
    }
}

extern "C" void kernel_launch(void* const* d_in, const int* in_sizes, int n_in,
                              void* d_out, int out_size, void* d_ws, size_t ws_size,
                              hipStream_t stream) {
    const float* x    = (const float*)d_in[0];
    const float* nw   = (const float*)d_in[1];
    const float* nb   = (const float*)d_in[2];
    const float* wqkv = (const float*)d_in[3];
    const float* wout = (const float*)d_in[4];
    const float* bout = (const float*)d_in[5];
    float* out = (float*)d_out;
    char* wsb = (char*)d_ws;

    unsigned short* qkT = (unsigned short*)wsb;                        // 8 MB: [2][B][H][4096][32]
    unsigned short* vbf = (unsigned short*)(wsb + 8u * 1024 * 1024);   // 4 MB: [B][H][32][4096]
    float* pO   = (float*)(wsb + 12u * 1024 * 1024);                   // 16 MB: [2ch][B][C][N]; ch0 doubles as att
    float* att  = pO;
    float* pl   = (float*)(wsb + 28u * 1024 * 1024);                   // 512 KB: [2ch][B][H][N]
    float* part = (float*)(wsb + 29u * 1024 * 1024);
    float* stats = part + 1024;

    k_stats_partial<<<512, 256, 0, stream>>>(x, part);
    k_stats_final<<<16, 64, 0, stream>>>(part, stats);
    k_qkv<<<dim3(NT / 64, 768 / 64, NB), 256, 0, stream>>>(x, wqkv, nw, nb, stats, qkT, vbf);
    k_attn<<<dim3(32, NH, NB * NCHUNK), 256, 0, stream>>>(qkT, vbf, pO, pl);
    k_combine<<<2048, 256, 0, stream>>>(pO, pl, att);
    k_out<<<dim3(NT / 64, NC / 64, NB), 256, 0, stream>>>(att, wout, bout, x, out);
}